// Round 4
// baseline (134.012 us; speedup 1.0000x reference)
//
#include <hip/hip_runtime.h>

// DIAGNOSTIC ROUND: R2's kernel (best so far, 15.03 us) wrapped in an
// in-kernel x12 repeat so the dispatch outlasts the harness's 40 us fills and
// finally shows up in the top-5 rocprof rows. Runtime-zero `izero`/`jitter`
// (host passes 0 / 0.0f) are folded into load indices and exp arguments so the
// compiler cannot hoist/CSE across iterations; every iteration computes and
// stores the identical (correct) output, so correctness and determinism hold.
//
// Read-out: per-iter kernel time k = dispatch_dur/12.
//   k <= ~6 us  -> R2 was already at the memory floor; the ~10 us residual in
//                  dur_us is graph/launch overhead -> revert to R2, ROOFLINE.
//   k >  ~10 us -> counters (VALUBusy / FETCH / conflicts / occupancy) say
//                  which pipe to fix next.

constexpr int kD = 64, kIC = 32, kOC = 32, kR = 8;
constexpr int kNT = 32;   // n rows per block
constexpr int PAD = 36, PQ = PAD / 4;

__global__ __launch_bounds__(256) void lse_kernel(
    const float* __restrict__ x, const float* __restrict__ w,
    float* __restrict__ out, int reps, int izero, float jitter)
{
    __shared__ __align__(16) float ws[kIC * kR * PAD];   // 36 KiB
    __shared__ __align__(16) float xs[kNT * kR * PAD];   // 36 KiB

    const int t  = threadIdx.x;
    const int d  = blockIdx.x;
    const int n0 = blockIdx.y * kNT;

    #pragma unroll 1
    for (int it = 0; it < reps; ++it) {
        const float jit = jitter * (float)it;   // runtime 0.0f
        const int   off = izero * it;           // runtime 0

        // ---- stage exp(weights[d]): global [ic][oc][r] -> ws [ic*8+r][j]
        {
            const float4* wg = reinterpret_cast<const float4*>(
                w + (size_t)d * (kIC * kOC * kR));
            #pragma unroll
            for (int i = 0; i < 8; ++i) {
                const int qg = i * 256 + t;
                float4 v = wg[qg + off];
                const int lin = qg * 4;
                const int ic = lin >> 8;
                const int oc = (lin >> 3) & 31;
                const int r0 = lin & 7;
                const int j  = (oc & 3) * 8 + (oc >> 2);
                float* p = &ws[(ic * kR + r0) * PAD + j];
                p[0 * PAD] = __expf(v.x + jit);
                p[1 * PAD] = __expf(v.y + jit);
                p[2 * PAD] = __expf(v.z + jit);
                p[3 * PAD] = __expf(v.w + jit);
            }
        }

        // ---- stage exp(x[n0..n0+31, d]): global [ic][r] -> xs [nl*8+r][ic]
        {
            #pragma unroll
            for (int i = 0; i < 8; ++i) {
                const int fidx = i * 256 + t;
                const int nl = fidx >> 6;
                const int e  = fidx & 63;
                const float4* xg = reinterpret_cast<const float4*>(
                    x + (size_t)(n0 + nl) * (kD * kIC * kR) + (size_t)d * (kIC * kR));
                float4 v = xg[e + off];
                const int ic = e >> 1;
                const int r0 = (e & 1) * 4;
                float* p = &xs[(nl * kR + r0) * PAD + ic];
                p[0 * PAD] = __expf(v.x + jit);
                p[1 * PAD] = __expf(v.y + jit);
                p[2 * PAD] = __expf(v.z + jit);
                p[3 * PAD] = __expf(v.w + jit);
            }
        }

        __syncthreads();

        // ---- compute: thread (rr, och, ng) owns 4 n x 8 oc x r=rr
        const int rr  = t & 7;
        const int och = (t >> 3) & 3;
        const int ng  = t >> 5;

        float acc[4][8];
        #pragma unroll
        for (int jj = 0; jj < 4; ++jj)
            #pragma unroll
            for (int k = 0; k < 8; ++k)
                acc[jj][k] = 0.f;

        const float4* xs4 = reinterpret_cast<const float4*>(xs);
        const float4* ws4 = reinterpret_cast<const float4*>(ws);

        #pragma unroll
        for (int icq = 0; icq < 8; ++icq) {
            float4 xv[4];
            #pragma unroll
            for (int jj = 0; jj < 4; ++jj)
                xv[jj] = xs4[((ng * 4 + jj) * kR + rr) * PQ + icq];
            #pragma unroll
            for (int q = 0; q < 4; ++q) {
                const int ic = icq * 4 + q;
                const float4 w0 = ws4[(ic * kR + rr) * PQ + och * 2];
                const float4 w1 = ws4[(ic * kR + rr) * PQ + och * 2 + 1];
                #pragma unroll
                for (int jj = 0; jj < 4; ++jj) {
                    const float xq = reinterpret_cast<const float*>(&xv[jj])[q];
                    acc[jj][0] = fmaf(xq, w0.x, acc[jj][0]);
                    acc[jj][1] = fmaf(xq, w0.y, acc[jj][1]);
                    acc[jj][2] = fmaf(xq, w0.z, acc[jj][2]);
                    acc[jj][3] = fmaf(xq, w0.w, acc[jj][3]);
                    acc[jj][4] = fmaf(xq, w1.x, acc[jj][4]);
                    acc[jj][5] = fmaf(xq, w1.y, acc[jj][5]);
                    acc[jj][6] = fmaf(xq, w1.z, acc[jj][6]);
                    acc[jj][7] = fmaf(xq, w1.w, acc[jj][7]);
                }
            }
        }

        // ---- store
        #pragma unroll
        for (int jj = 0; jj < 4; ++jj) {
            const int n = n0 + ng * 4 + jj;
            float* op = out + (size_t)n * (kD * kOC * kR) + (size_t)d * (kOC * kR)
                        + och * 8 + rr;
            #pragma unroll
            for (int k = 0; k < 8; ++k)
                op[k * 32] = __logf(acc[jj][k]);
        }

        __syncthreads();   // protect LDS from next iteration's staging
    }
}

extern "C" void kernel_launch(void* const* d_in, const int* in_sizes, int n_in,
                              void* d_out, int out_size, void* d_ws, size_t ws_size,
                              hipStream_t stream) {
    const float* x = (const float*)d_in[0];
    const float* w = (const float*)d_in[1];
    float* out = (float*)d_out;
    dim3 grid(kD, 256 / kNT);
    lse_kernel<<<grid, 256, 0, stream>>>(x, w, out, 12, 0, 0.0f);
}

// Round 5
// 13.537 us; speedup vs baseline: 9.8998x; 9.8998x over previous
//
#include <hip/hip_runtime.h>

// out[n,d,oc,r] = logsumexp_ic( x[n,0,d,ic,r] + w[d,ic,oc,r] )
//              = log( sum_ic exp(x) * exp(w) )
// After exponentiation this is a batched GEMM over (d,r): K=IC=32 exactly
// matches one v_mfma_f32_16x16x32_bf16 -> no K-loop, no VALU FMAs.
//
// Block = (d, 32 n), 256 threads (4 waves), grid 64x8 = 512 blocks = 2/CU.
// Staging: exp() in fp32, RTNE to bf16, packed ds_write_b32 directly into
// MFMA fragment order (lane&15 = row/col, slots = 8 contiguous ic per l>>4).
// Each wave owns quadrant (n-tile wt, oc-tile wu) and runs 8 r-MFMAs; frag
// reads are contiguous ds_read_b128 (conflict-free). Epilogue: log + float4
// stores (r 0..7 contiguous per (n,oc)).

typedef __attribute__((ext_vector_type(8))) short bf16x8;
typedef __attribute__((ext_vector_type(4))) float f32x4;

constexpr int kD = 64, kIC = 32, kOC = 32, kR = 8;
constexpr int kNT = 32;

__device__ __forceinline__ unsigned short f2bf(float f) {
    unsigned u = __builtin_bit_cast(unsigned, f);
    u += 0x7FFFu + ((u >> 16) & 1u);          // RTNE (inputs positive finite)
    return (unsigned short)(u >> 16);
}

__global__ __launch_bounds__(256) void lse_kernel(
    const float* __restrict__ x, const float* __restrict__ w,
    float* __restrict__ out)
{
    // frag-ordered bf16 tiles: [tile(2)][r(8)][lane(64)][slot(8)]
    __shared__ __align__(16) unsigned short xs[2 * 8 * 64 * 8];   // 16 KiB
    __shared__ __align__(16) unsigned short wsm[2 * 8 * 64 * 8];  // 16 KiB

    const int t  = threadIdx.x;
    const int d  = blockIdx.x;
    const int n0 = blockIdx.y * kNT;

    const int c  = t & 7;
    const int ch = c & 1;          // r-half: r = 4*ch + j
    const int cq = c >> 1;         // 0..3
    const int nl = t >> 3;         // x: n row 0..31  /  w: oc 0..31

    // ---- issue all 16 global loads up front (ILP hides L2/HBM latency)
    const float* xrow = x + (size_t)(n0 + nl) * (kD * kIC * kR) + (size_t)d * (kIC * kR);
    const float* wd   = w + (size_t)d * (kIC * kOC * kR);
    float4 xv[8], wv[8];
    #pragma unroll
    for (int a = 0; a < 4; ++a) {
        const int ic0 = 8 * a + 2 * cq;                   // even; pair (ic0, ic0+1)
        xv[2*a]   = *reinterpret_cast<const float4*>(xrow + ic0 * 8 + 4 * ch);
        xv[2*a+1] = *reinterpret_cast<const float4*>(xrow + ic0 * 8 + 8 + 4 * ch);
        wv[2*a]   = *reinterpret_cast<const float4*>(wd + (size_t)ic0 * 256 + nl * 8 + 4 * ch);
        wv[2*a+1] = *reinterpret_cast<const float4*>(wd + (size_t)(ic0 + 1) * 256 + nl * 8 + 4 * ch);
    }

    // ---- exp -> bf16 -> frag-ordered LDS (b32 packed pairs; 2-way banks = free)
    {
        const int row = nl & 15, tt = nl >> 4, s0 = 2 * cq;   // q = a, s = s0(,+1)
        #pragma unroll
        for (int a = 0; a < 4; ++a)
            #pragma unroll
            for (int j = 0; j < 4; ++j) {
                const int r = 4 * ch + j;
                const unsigned pk =
                    (unsigned)f2bf(__expf(reinterpret_cast<const float*>(&xv[2*a])[j])) |
                    ((unsigned)f2bf(__expf(reinterpret_cast<const float*>(&xv[2*a+1])[j])) << 16);
                *reinterpret_cast<unsigned*>(&xs[((tt * 8 + r) * 64 + a * 16 + row) * 8 + s0]) = pk;
            }
    }
    {
        const int col = nl & 15, u = nl >> 4, s0 = 2 * cq;
        #pragma unroll
        for (int a = 0; a < 4; ++a)
            #pragma unroll
            for (int j = 0; j < 4; ++j) {
                const int r = 4 * ch + j;
                const unsigned pk =
                    (unsigned)f2bf(__expf(reinterpret_cast<const float*>(&wv[2*a])[j])) |
                    ((unsigned)f2bf(__expf(reinterpret_cast<const float*>(&wv[2*a+1])[j])) << 16);
                *reinterpret_cast<unsigned*>(&wsm[((u * 8 + r) * 64 + a * 16 + col) * 8 + s0]) = pk;
            }
    }

    __syncthreads();

    // ---- MFMA: wave (wt, wu) quadrant, 8 independent r-outputs (K=32 each)
    const int wave = t >> 6;
    const int wt = wave & 1;       // n-tile
    const int wu = wave >> 1;      // oc-tile
    const int l  = t & 63;

    f32x4 acc[8];
    #pragma unroll
    for (int r = 0; r < 8; ++r) {
        bf16x8 av = *reinterpret_cast<const bf16x8*>(&xs[(wt * 8 + r) * 512 + l * 8]);
        bf16x8 bv = *reinterpret_cast<const bf16x8*>(&wsm[(wu * 8 + r) * 512 + l * 8]);
        f32x4 z = {0.f, 0.f, 0.f, 0.f};
        acc[r] = __builtin_amdgcn_mfma_f32_16x16x32_bf16(av, bv, z, 0, 0, 0);
    }

    // ---- epilogue: log + store (C/D: col = l&15, row = (l>>4)*4 + reg)
    const int colL = l & 15, qL = l >> 4;
    float* opb = out + (size_t)d * (kOC * kR) + (size_t)(wu * 16 + colL) * 8;
    #pragma unroll
    for (int i = 0; i < 4; ++i) {
        const int n = n0 + wt * 16 + qL * 4 + i;
        float* op = opb + (size_t)n * (kD * kOC * kR);
        float4 v0, v1;
        v0.x = __logf(acc[0][i]); v0.y = __logf(acc[1][i]);
        v0.z = __logf(acc[2][i]); v0.w = __logf(acc[3][i]);
        v1.x = __logf(acc[4][i]); v1.y = __logf(acc[5][i]);
        v1.z = __logf(acc[6][i]); v1.w = __logf(acc[7][i]);
        *reinterpret_cast<float4*>(op)     = v0;
        *reinterpret_cast<float4*>(op + 4) = v1;
    }
}

extern "C" void kernel_launch(void* const* d_in, const int* in_sizes, int n_in,
                              void* d_out, int out_size, void* d_ws, size_t ws_size,
                              hipStream_t stream) {
    const float* x = (const float*)d_in[0];
    const float* w = (const float*)d_in[1];
    float* out = (float*)d_out;
    dim3 grid(kD, 256 / kNT);
    lse_kernel<<<grid, 256, 0, stream>>>(x, w, out);
}

// Round 6
// 12.964 us; speedup vs baseline: 10.3373x; 1.0442x over previous
//
#include <hip/hip_runtime.h>

// out[n,d,oc,r] = logsumexp_ic( x[n,0,d,ic,r] + w[d,ic,oc,r] )
//              = log( sum_ic exp(x) * exp(w) )
// Batched GEMM over (d,r): K=IC=32 = one v_mfma_f32_16x16x32_bf16 per tile.
//
// R6: 2-chunk software pipeline to interleave HBM reads and writes.
// Block = (d, 32n), 256 threads (4 waves), grid 64x8 = 512 = 2 blocks/CU.
// Issue ALL global loads up front (w, x0, x1); stage w+x0; barrier; MFMA c0;
// stage x1; store c0 (drains under c1 compute); barrier; MFMA c1; store c1.
// Waves split (oc-half, r-half): 4 MFMAs per wave per chunk.

typedef __attribute__((ext_vector_type(8))) short bf16x8;
typedef __attribute__((ext_vector_type(4))) float f32x4;

constexpr int kD = 64, kIC = 32, kOC = 32, kR = 8;

__device__ __forceinline__ unsigned short f2bf(float f) {
    unsigned u = __builtin_bit_cast(unsigned, f);
    u += 0x7FFFu + ((u >> 16) & 1u);          // RTNE (inputs positive finite)
    return (unsigned short)(u >> 16);
}

__global__ __launch_bounds__(256) void lse_kernel(
    const float* __restrict__ x, const float* __restrict__ w,
    float* __restrict__ out)
{
    // frag-ordered bf16: ws [oc-tile u][r][lane][slot8], xs [chunk][r][lane][slot8]
    __shared__ __align__(16) unsigned short wsm[2 * 8 * 64 * 8];  // 16 KiB
    __shared__ __align__(16) unsigned short xs[2 * 8 * 64 * 8];   // 16 KiB

    const int t  = threadIdx.x;
    const int d  = blockIdx.x;
    const int n0 = blockIdx.y * 32;

    // ---------------- issue ALL global loads up front ----------------
    // w: thread (ol = t>>3 -> oc 0..31, cw = t&7 -> chw = r-half, cqw)
    const int cw = t & 7, chw = cw & 1, cqw = cw >> 1, ol = t >> 3;
    const float* wd = w + (size_t)d * (kIC * kOC * kR);
    float4 wv[8];
    #pragma unroll
    for (int a = 0; a < 4; ++a) {
        const int ic0 = 8 * a + 2 * cqw;
        wv[2*a]   = *reinterpret_cast<const float4*>(wd + (size_t)ic0 * 256 + ol * 8 + 4 * chw);
        wv[2*a+1] = *reinterpret_cast<const float4*>(wd + (size_t)(ic0 + 1) * 256 + ol * 8 + 4 * chw);
    }

    // x: thread (nlx = t>>4 -> row 0..15, cx = t&15 -> e = r-half, icp)
    const int cx = t & 15, e = cx & 1, icp = cx >> 1, nlx = t >> 4;
    const float* xr0 = x + (size_t)(n0 + nlx) * (kD * kIC * kR) + (size_t)d * (kIC * kR);
    const float* xr1 = xr0 + (size_t)16 * (kD * kIC * kR);
    float4 x0v[4], x1v[4];
    #pragma unroll
    for (int a = 0; a < 2; ++a) {
        const int ic0 = 16 * a + 2 * icp;
        x0v[2*a]   = *reinterpret_cast<const float4*>(xr0 + ic0 * 8 + 4 * e);
        x0v[2*a+1] = *reinterpret_cast<const float4*>(xr0 + ic0 * 8 + 8 + 4 * e);
        x1v[2*a]   = *reinterpret_cast<const float4*>(xr1 + ic0 * 8 + 4 * e);
        x1v[2*a+1] = *reinterpret_cast<const float4*>(xr1 + ic0 * 8 + 8 + 4 * e);
    }

    // ---------------- stage w: exp -> bf16 pairs -> frag order ----------------
    {
        const int col = ol & 15, u = ol >> 4, s0 = 2 * cqw;
        #pragma unroll
        for (int a = 0; a < 4; ++a)
            #pragma unroll
            for (int j = 0; j < 4; ++j) {
                const int r = 4 * chw + j;
                const unsigned pk =
                    (unsigned)f2bf(__expf(reinterpret_cast<const float*>(&wv[2*a])[j])) |
                    ((unsigned)f2bf(__expf(reinterpret_cast<const float*>(&wv[2*a+1])[j])) << 16);
                *reinterpret_cast<unsigned*>(&wsm[((u * 8 + r) * 64 + a * 16 + col) * 8 + s0]) = pk;
            }
    }

    // staging helper for an x chunk (c is a compile-time literal at call sites)
    const int icg = 2 * 0 + 0; (void)icg;   // (computed inline below)
    auto stage_x = [&](int c, const float4* xcv) {
        const int ig_lo = icp >> 2;                 // 0/1
        const int s0x = 2 * (icp & 3);
        #pragma unroll
        for (int a = 0; a < 2; ++a) {
            const int g = 2 * a + ig_lo;            // ic-group 0..3
            const int lane = g * 16 + nlx;
            #pragma unroll
            for (int j = 0; j < 4; ++j) {
                const int r = 4 * e + j;
                const unsigned pk =
                    (unsigned)f2bf(__expf(reinterpret_cast<const float*>(&xcv[2*a])[j])) |
                    ((unsigned)f2bf(__expf(reinterpret_cast<const float*>(&xcv[2*a+1])[j])) << 16);
                *reinterpret_cast<unsigned*>(&xs[((c * 8 + r) * 64 + lane) * 8 + s0x]) = pk;
            }
        }
    };

    stage_x(0, x0v);
    __syncthreads();

    // ---------------- compute/store helpers ----------------
    const int wave = t >> 6;
    const int wu = wave & 1;       // oc-tile
    const int wr = wave >> 1;      // r-half
    const int l  = t & 63;
    const int colL = l & 15, qL = l >> 4;

    f32x4 acc0[4], acc1[4];
    auto compute = [&](int c, f32x4* acc) {
        #pragma unroll
        for (int j = 0; j < 4; ++j) {
            const int r = wr * 4 + j;
            bf16x8 av = *reinterpret_cast<const bf16x8*>(&xs[((c * 8 + r) * 64 + l) * 8]);
            bf16x8 bv = *reinterpret_cast<const bf16x8*>(&wsm[((wu * 8 + r) * 64 + l) * 8]);
            f32x4 z = {0.f, 0.f, 0.f, 0.f};
            acc[j] = __builtin_amdgcn_mfma_f32_16x16x32_bf16(av, bv, z, 0, 0, 0);
        }
    };
    auto logstore = [&](int c, const f32x4* acc) {
        #pragma unroll
        for (int i = 0; i < 4; ++i) {
            const int n = n0 + c * 16 + qL * 4 + i;
            float4 v;
            v.x = __logf(acc[0][i]); v.y = __logf(acc[1][i]);
            v.z = __logf(acc[2][i]); v.w = __logf(acc[3][i]);
            *reinterpret_cast<float4*>(out + (size_t)n * (kD * kOC * kR)
                + (size_t)d * (kOC * kR) + (size_t)(wu * 16 + colL) * 8 + wr * 4) = v;
        }
    };

    // ---------------- pipelined chunks ----------------
    compute(0, acc0);
    stage_x(1, x1v);               // x1 loads arrived long ago; pure VALU+ds_write
    logstore(0, acc0);             // stores drain while chunk1 is staged/computed
    __syncthreads();
    compute(1, acc1);
    logstore(1, acc1);
}

extern "C" void kernel_launch(void* const* d_in, const int* in_sizes, int n_in,
                              void* d_out, int out_size, void* d_ws, size_t ws_size,
                              hipStream_t stream) {
    const float* x = (const float*)d_in[0];
    const float* w = (const float*)d_in[1];
    float* out = (float*)d_out;
    dim3 grid(kD, 8);
    lse_kernel<<<grid, 256, 0, stream>>>(x, w, out);
}